// Round 6
// baseline (2629.001 us; speedup 1.0000x reference)
//
#include <hip/hip_runtime.h>
#include <hip/hip_bf16.h>
#include <math.h>

#define N_NODES 100000
#define N_EDGES 1600000
#define IN_F 256
#define HID 32
#define OUTC 16
#define NBLK_SCAN 98   // ceil(100000/1024)
#define NBUCK 8
#define BUCK_W 12500   // N_NODES / NBUCK

typedef unsigned short ushort_t;
typedef unsigned int uint_t;
typedef unsigned long long ull_t;

__device__ inline ushort_t f2bf(float f) {
    union { float f; uint_t u; } v; v.f = f;
    uint_t r = v.u + 0x7fff + ((v.u >> 16) & 1);   // round-to-nearest-even
    return (ushort_t)(r >> 16);
}
__device__ inline float bf2f(ushort_t h) {
    union { uint_t u; float f; } v; v.u = (uint_t)h << 16;
    return v.f;
}

// ============ CSR build ============
__global__ __launch_bounds__(256) void k_zero(int* __restrict__ deg)
{
    const int i = blockIdx.x * 256 + threadIdx.x;
    if (i <= N_NODES) deg[i] = 0;
}

__global__ __launch_bounds__(256) void k_hist(const int* __restrict__ ei, int* __restrict__ deg)
{
    const int e = blockIdx.x * 256 + threadIdx.x;
    const int dst = ei[N_EDGES + e];
    atomicAdd(&deg[dst], 1);
}

__global__ __launch_bounds__(1024) void k_scanA(const int* __restrict__ deg,
                                                int* __restrict__ part, int* __restrict__ bsum)
{
    __shared__ int sh[1024];
    const int t = threadIdx.x;
    const int idx = blockIdx.x * 1024 + t;
    const int v = (idx < N_NODES) ? deg[idx] : 0;
    sh[t] = v;
    __syncthreads();
    #pragma unroll
    for (int off = 1; off < 1024; off <<= 1) {
        const int u = (t >= off) ? sh[t - off] : 0;
        __syncthreads();
        sh[t] += u;
        __syncthreads();
    }
    if (idx < N_NODES) part[idx] = sh[t] - v;
    if (t == 1023) bsum[blockIdx.x] = sh[1023];
}

__global__ __launch_bounds__(128) void k_scanB(int* __restrict__ bsum, int* __restrict__ boff,
                                               int* __restrict__ row_start)
{
    __shared__ int sh[128];
    const int t = threadIdx.x;
    const int v = (t < NBLK_SCAN) ? bsum[t] : 0;
    sh[t] = v;
    __syncthreads();
    #pragma unroll
    for (int off = 1; off < 128; off <<= 1) {
        const int u = (t >= off) ? sh[t - off] : 0;
        __syncthreads();
        sh[t] += u;
        __syncthreads();
    }
    if (t < NBLK_SCAN) boff[t] = sh[t] - v;
    if (t == 127) row_start[N_NODES] = sh[127];
}

// row_start = part + boff ; cursor = row_start ; bucket cursors seeded at bucket starts
__global__ __launch_bounds__(1024) void k_scanC(const int* __restrict__ part,
                                                const int* __restrict__ boff,
                                                int* __restrict__ row_start,
                                                int* __restrict__ cursor,
                                                int* __restrict__ bcur)
{
    const int idx = blockIdx.x * 1024 + threadIdx.x;
    if (idx < N_NODES) {
        const int v = part[idx] + boff[blockIdx.x];
        row_start[idx] = v;
        cursor[idx]    = v;
        if ((idx % BUCK_W) == 0) bcur[idx / BUCK_W] = v;
    }
}

// Phase 1: wave-aggregated 8-way multisplit of edges by dst bucket -> pairs (bucket-contiguous)
__global__ __launch_bounds__(256) void k_bin(const int* __restrict__ ei,
                                             int* __restrict__ bcur, int2* __restrict__ pairs)
{
    const int lane = threadIdx.x & 63;
    const int wid  = (blockIdx.x * 256 + threadIdx.x) >> 6;
    const int nw   = (gridDim.x * 256) >> 6;
    for (int base = wid * 64; base < N_EDGES; base += nw * 64) {
        const int e   = base + lane;               // N_EDGES % 64 == 0
        const int src = ei[e];
        const int dst = ei[N_EDGES + e];
        const int b   = dst / BUCK_W;
        #pragma unroll
        for (int bb = 0; bb < NBUCK; ++bb) {
            const ull_t m = __ballot(b == bb);
            if (m == 0ull) continue;
            const int cnt = __popcll(m);
            const int ldr = __ffsll((long long)m) - 1;
            int pos0 = 0;
            if (lane == ldr) pos0 = atomicAdd(&bcur[bb], cnt);
            pos0 = __shfl(pos0, ldr);
            if (b == bb) {
                const int off = __popcll(m & ((1ull << lane) - 1ull));
                pairs[pos0 + off] = make_int2(dst, src);
            }
        }
    }
}

// Phase 2: per-bucket fill; blockIdx%8 -> bucket -> (default round-robin) XCD-local col writes
__global__ __launch_bounds__(256) void k_fill2(const int* __restrict__ row_start,
                                               const int2* __restrict__ pairs,
                                               int* __restrict__ cursor, int* __restrict__ col)
{
    const int bucket = blockIdx.x & (NBUCK - 1);
    const int tile   = blockIdx.x >> 3;
    const int ntiles = gridDim.x >> 3;
    const int s  = row_start[bucket * BUCK_W];
    const int en = (bucket == NBUCK - 1) ? N_EDGES : row_start[(bucket + 1) * BUCK_W];
    for (int i = s + tile * 256 + threadIdx.x; i < en; i += ntiles * 256) {
        const int2 p = pairs[i];
        const int pos = atomicAdd(&cursor[p.x], 1);
        col[pos] = p.y;
    }
}

// ============ Layer 1: h1 = x@W1a^T + b ; out1 = h1@W1b^T + b ============
__global__ __launch_bounds__(256) void k1_layer1_dense(
    const float* __restrict__ x,
    const float* __restrict__ w1a_w, const float* __restrict__ w1a_b,
    const float* __restrict__ w1b_w, const float* __restrict__ w1b_b,
    ushort_t* __restrict__ h1b, float* __restrict__ out1)
{
    __shared__ float ws[32][256];
    __shared__ float hs[256][36];
    __shared__ float wbs[32][32];

    const int t  = threadIdx.x;
    const int og = t & 3;
    const int ng = t >> 2;
    const int o0 = og * 8;
    const int node0 = blockIdx.x * 256;

    {
        const float4* wsrc = (const float4*)w1a_w;
        float4* wdst = (float4*)&ws[0][0];
        for (int i = t; i < 2048; i += 256) wdst[i] = wsrc[i];
        const float4* bsrc = (const float4*)w1b_w;
        float4* bdst = (float4*)&wbs[0][0];
        if (t < 256) bdst[t] = bsrc[t];
    }
    __syncthreads();

    int nid[4]; bool val[4];
    #pragma unroll
    for (int j = 0; j < 4; ++j) { nid[j] = node0 + ng * 4 + j; val[j] = nid[j] < N_NODES; }

    float acc[4][8] = {};
    for (int kc = 0; kc < 64; kc += 2) {
        float4 xs4[4][2];
        #pragma unroll
        for (int j = 0; j < 4; ++j) {
            if (val[j]) {
                const float4* xr = (const float4*)(x + (size_t)nid[j] * IN_F);
                xs4[j][0] = xr[kc];
                xs4[j][1] = xr[kc + 1];
            } else {
                xs4[j][0] = make_float4(0.f, 0.f, 0.f, 0.f);
                xs4[j][1] = make_float4(0.f, 0.f, 0.f, 0.f);
            }
        }
        #pragma unroll
        for (int u = 0; u < 2; ++u) {
            const int k4 = (kc + u) * 4;
            #pragma unroll
            for (int o = 0; o < 8; ++o) {
                const float4 w4 = *(const float4*)&ws[o0 + o][k4];
                #pragma unroll
                for (int j = 0; j < 4; ++j) {
                    acc[j][o] += xs4[j][u].x * w4.x + xs4[j][u].y * w4.y
                               + xs4[j][u].z * w4.z + xs4[j][u].w * w4.w;
                }
            }
        }
    }

    #pragma unroll
    for (int o = 0; o < 8; ++o) {
        const float b = w1a_b[o0 + o];
        #pragma unroll
        for (int j = 0; j < 4; ++j) acc[j][o] += b;
    }

    #pragma unroll
    for (int j = 0; j < 4; ++j) {
        const int ln = ng * 4 + j;
        *(float4*)&hs[ln][o0]     = make_float4(acc[j][0], acc[j][1], acc[j][2], acc[j][3]);
        *(float4*)&hs[ln][o0 + 4] = make_float4(acc[j][4], acc[j][5], acc[j][6], acc[j][7]);
        if (val[j]) {
            uint4 pk;
            pk.x = (uint_t)f2bf(acc[j][0]) | ((uint_t)f2bf(acc[j][1]) << 16);
            pk.y = (uint_t)f2bf(acc[j][2]) | ((uint_t)f2bf(acc[j][3]) << 16);
            pk.z = (uint_t)f2bf(acc[j][4]) | ((uint_t)f2bf(acc[j][5]) << 16);
            pk.w = (uint_t)f2bf(acc[j][6]) | ((uint_t)f2bf(acc[j][7]) << 16);
            *(uint4*)(h1b + (size_t)nid[j] * HID + o0) = pk;
        }
    }
    __syncthreads();

    float f[4][8] = {};
    #pragma unroll 2
    for (int c4 = 0; c4 < 8; ++c4) {
        float4 h4[4];
        #pragma unroll
        for (int j = 0; j < 4; ++j) h4[j] = *(const float4*)&hs[ng * 4 + j][c4 * 4];
        #pragma unroll
        for (int o = 0; o < 8; ++o) {
            const float4 w4 = *(const float4*)&wbs[o0 + o][c4 * 4];
            #pragma unroll
            for (int j = 0; j < 4; ++j)
                f[j][o] += h4[j].x * w4.x + h4[j].y * w4.y + h4[j].z * w4.z + h4[j].w * w4.w;
        }
    }
    #pragma unroll
    for (int o = 0; o < 8; ++o) {
        const float b = w1b_b[o0 + o];
        #pragma unroll
        for (int j = 0; j < 4; ++j) f[j][o] += b;
    }
    #pragma unroll
    for (int j = 0; j < 4; ++j) {
        if (val[j]) {
            float* dst = out1 + (size_t)nid[j] * HID + o0;
            *(float4*)dst       = make_float4(f[j][0], f[j][1], f[j][2], f[j][3]);
            *(float4*)(dst + 4) = make_float4(f[j][4], f[j][5], f[j][6], f[j][7]);
        }
    }
}

// ============ Gather-aggregate layer 1 (bf16 h1) ============
__global__ __launch_bounds__(256) void k_agg32(const int* __restrict__ row_start,
                                               const int* __restrict__ col,
                                               const ushort_t* __restrict__ h1b,
                                               float* __restrict__ out1)
{
    const int t = threadIdx.x;
    const int n = blockIdx.x * 8 + (t >> 5);
    const int c = t & 31;
    if (n >= N_NODES) return;
    const int e0 = row_start[n];
    const int e1 = row_start[n + 1];
    float acc = 0.f;
    for (int e = e0; e < e1; ++e) {
        const int s = col[e];
        acc += bf2f(h1b[(size_t)s * HID + c]);
    }
    out1[(size_t)n * HID + c] += acc;
}

// ============ Layer 2 dense ============
__global__ __launch_bounds__(256) void k3_layer2_dense(
    const float* __restrict__ out1,
    const float* __restrict__ w2a_w, const float* __restrict__ w2a_b,
    const float* __restrict__ w2b_w, const float* __restrict__ w2b_b,
    ushort_t* __restrict__ h2b, float* __restrict__ out2)
{
    __shared__ float rs[64][33];
    __shared__ float h2s[64][17];
    __shared__ float wa[16][33];
    __shared__ float wb[16][17];

    const int t = threadIdx.x;
    const int node0 = blockIdx.x * 64;
    const int nrem = N_NODES - node0;

    for (int i = t; i < 16 * 32; i += 256)
        wa[i >> 5][i & 31] = w2a_w[i];
    if (t < 16 * 16) wb[t >> 4][t & 15] = w2b_w[t];
    for (int i = t; i < 64 * 32; i += 256) {
        int r = i >> 5, c = i & 31;
        float v = 0.f;
        if (r < nrem) v = out1[(size_t)(node0 + r) * HID + c];
        rs[r][c] = fmaxf(v, 0.f);
    }
    __syncthreads();

    const int o = t & 15;
    const int g = t >> 4;

    const float ba = w2a_b[o];
    float acc[4] = {};
    for (int c = 0; c < 32; ++c) {
        const float w = wa[o][c];
        #pragma unroll
        for (int j = 0; j < 4; ++j) acc[j] += rs[g * 4 + j][c] * w;
    }
    #pragma unroll
    for (int j = 0; j < 4; ++j) {
        const int ln = g * 4 + j;
        const float v = acc[j] + ba;
        h2s[ln][o] = v;
        if (ln < nrem) h2b[(size_t)(node0 + ln) * OUTC + o] = f2bf(v);
    }
    __syncthreads();

    const float bbv = w2b_b[o];
    float f[4] = {};
    for (int c = 0; c < 16; ++c) {
        const float w = wb[o][c];
        #pragma unroll
        for (int j = 0; j < 4; ++j) f[j] += h2s[g * 4 + j][c] * w;
    }
    #pragma unroll
    for (int j = 0; j < 4; ++j) {
        const int ln = g * 4 + j;
        if (ln < nrem) out2[(size_t)(node0 + ln) * OUTC + o] = f[j] + bbv;
    }
}

// ============ Gather-aggregate layer 2 (bf16 h2) + fused log_softmax ============
__global__ __launch_bounds__(256) void k_agg16_sm(const int* __restrict__ row_start,
                                                  const int* __restrict__ col,
                                                  const ushort_t* __restrict__ h2b,
                                                  float* __restrict__ out2)
{
    const int t = threadIdx.x;
    const int n = blockIdx.x * 16 + (t >> 4);
    const int c = t & 15;
    if (n >= N_NODES) return;
    const int e0 = row_start[n];
    const int e1 = row_start[n + 1];
    float acc = 0.f;
    for (int e = e0; e < e1; ++e) {
        const int s = col[e];
        acc += bf2f(h2b[(size_t)s * OUTC + c]);
    }
    const float val = out2[(size_t)n * OUTC + c] + acc;

    float m = val;
    #pragma unroll
    for (int off = 8; off > 0; off >>= 1)
        m = fmaxf(m, __shfl_xor(m, off, 16));
    float s = expf(val - m);
    #pragma unroll
    for (int off = 8; off > 0; off >>= 1)
        s += __shfl_xor(s, off, 16);
    const float lse = m + logf(s);
    out2[(size_t)n * OUTC + c] = val - lse;
}

extern "C" void kernel_launch(void* const* d_in, const int* in_sizes, int n_in,
                              void* d_out, int out_size, void* d_ws, size_t ws_size,
                              hipStream_t stream)
{
    const float* x      = (const float*)d_in[0];
    const float* w1a_w  = (const float*)d_in[1];
    const float* w1a_b  = (const float*)d_in[2];
    const float* w1b_w  = (const float*)d_in[3];
    const float* w1b_b  = (const float*)d_in[4];
    const float* w2a_w  = (const float*)d_in[5];
    const float* w2a_b  = (const float*)d_in[6];
    const float* w2b_w  = (const float*)d_in[7];
    const float* w2b_b  = (const float*)d_in[8];
    const int*   ei     = (const int*)d_in[9];
    float* out = (float*)d_out;

    // workspace (~33.2 MB):
    float* out1    = (float*)d_ws;                              // 12.8 MB
    int2*  pairs   = (int2*)(out1 + (size_t)N_NODES * HID);     // 12.8 MB (E int2)
    // h1b/h2b alias pairs (pairs dead before k1 runs):
    ushort_t* h1b  = (ushort_t*)pairs;                          // 6.4 MB
    ushort_t* h2b  = h1b + (size_t)N_NODES * HID;               // 3.2 MB
    int* deg_cur   = (int*)(pairs + N_EDGES);                   // N+1
    int* row_start = deg_cur + (N_NODES + 1);                   // N+1
    int* col       = row_start + (N_NODES + 1);                 // 6.4 MB
    int* part      = col + N_EDGES;                             // N
    int* bsum      = part + N_NODES;                            // NBLK_SCAN
    int* boff      = bsum + NBLK_SCAN;                          // NBLK_SCAN
    int* bcur      = boff + NBLK_SCAN;                          // NBUCK

    k_zero<<<(N_NODES + 256) / 256, 256, 0, stream>>>(deg_cur);
    k_hist<<<N_EDGES / 256, 256, 0, stream>>>(ei, deg_cur);
    k_scanA<<<NBLK_SCAN, 1024, 0, stream>>>(deg_cur, part, bsum);
    k_scanB<<<1, 128, 0, stream>>>(bsum, boff, row_start);
    k_scanC<<<NBLK_SCAN, 1024, 0, stream>>>(part, boff, row_start, deg_cur, bcur);
    k_bin<<<1024, 256, 0, stream>>>(ei, bcur, pairs);
    k_fill2<<<1024, 256, 0, stream>>>(row_start, pairs, deg_cur, col);

    k1_layer1_dense<<<(N_NODES + 255) / 256, 256, 0, stream>>>(x, w1a_w, w1a_b, w1b_w, w1b_b, h1b, out1);
    k_agg32<<<(N_NODES + 7) / 8, 256, 0, stream>>>(row_start, col, h1b, out1);
    k3_layer2_dense<<<(N_NODES + 63) / 64, 256, 0, stream>>>(out1, w2a_w, w2a_b, w2b_w, w2b_b, h2b, out);
    k_agg16_sm<<<(N_NODES + 15) / 16, 256, 0, stream>>>(row_start, col, h2b, out);
}

// Round 7
// 547.810 us; speedup vs baseline: 4.7991x; 4.7991x over previous
//
#include <hip/hip_runtime.h>
#include <hip/hip_bf16.h>
#include <math.h>

#define N_NODES 100000
#define N_EDGES 1600000
#define IN_F 256
#define HID 32
#define OUTC 16
#define NBUCK 500
#define BUCK_W 200     // NBUCK * BUCK_W == N_NODES
#define NBB 256        // partition blocks
#define CHUNK 6250     // N_EDGES / NBB

typedef unsigned short ushort_t;
typedef unsigned int uint_t;

__device__ inline ushort_t f2bf(float f) {
    union { float f; uint_t u; } v; v.f = f;
    uint_t r = v.u + 0x7fff + ((v.u >> 16) & 1);   // round-to-nearest-even
    return (ushort_t)(r >> 16);
}
__device__ inline float bf2f(ushort_t h) {
    union { uint_t u; float f; } v; v.u = (uint_t)h << 16;
    return v.f;
}

// ============ Pass 1: per-block bucket histogram (LDS only, no global atomics) ============
__global__ __launch_bounds__(256) void k_cnt(const int* __restrict__ ei, int* __restrict__ bhist)
{
    __shared__ int lh[NBUCK];
    const int t = threadIdx.x;
    const int blk = blockIdx.x;
    for (int b = t; b < NBUCK; b += 256) lh[b] = 0;
    __syncthreads();
    const int base = blk * CHUNK;
    for (int i = t; i < CHUNK; i += 256) {
        const int dst = ei[N_EDGES + base + i];
        atomicAdd(&lh[dst / BUCK_W], 1);
    }
    __syncthreads();
    for (int b = t; b < NBUCK; b += 256) bhist[b * NBB + blk] = lh[b];
}

// ============ Pass 2a: scan each bucket's 256 block-counts ============
__global__ __launch_bounds__(256) void k_scanH(const int* __restrict__ bhist,
                                               int* __restrict__ boffB, int* __restrict__ btot)
{
    __shared__ int sh[256];
    const int t = threadIdx.x;
    const int b = blockIdx.x;
    const int v = bhist[b * NBB + t];
    sh[t] = v;
    __syncthreads();
    #pragma unroll
    for (int off = 1; off < 256; off <<= 1) {
        const int u = (t >= off) ? sh[t - off] : 0;
        __syncthreads();
        sh[t] += u;
        __syncthreads();
    }
    boffB[b * NBB + t] = sh[t] - v;          // exclusive within bucket
    if (t == 255) btot[b] = sh[255];
}

// ============ Pass 2b: scan bucket totals -> bucket start offsets ============
__global__ __launch_bounds__(512) void k_scanH2(const int* __restrict__ btot,
                                                int* __restrict__ bstart)
{
    __shared__ int sh[512];
    const int t = threadIdx.x;
    const int v = (t < NBUCK) ? btot[t] : 0;
    sh[t] = v;
    __syncthreads();
    #pragma unroll
    for (int off = 1; off < 512; off <<= 1) {
        const int u = (t >= off) ? sh[t - off] : 0;
        __syncthreads();
        sh[t] += u;
        __syncthreads();
    }
    if (t < NBUCK) bstart[t] = sh[t] - v;
    if (t == NBUCK - 1) bstart[NBUCK] = sh[t];
}

// ============ Pass 3: scatter edges into bucket-contiguous packed pairs ============
// pairsP[pos] = (dst % BUCK_W) << 17 | src    (src < 2^17, dstLocal < 2^8)
__global__ __launch_bounds__(256) void k_scat(const int* __restrict__ ei,
                                              const int* __restrict__ boffB,
                                              const int* __restrict__ bstart,
                                              int* __restrict__ pairsP)
{
    __shared__ int lcur[NBUCK];
    const int t = threadIdx.x;
    const int blk = blockIdx.x;
    for (int b = t; b < NBUCK; b += 256) lcur[b] = bstart[b] + boffB[b * NBB + blk];
    __syncthreads();
    const int base = blk * CHUNK;
    for (int i = t; i < CHUNK; i += 256) {
        const int src = ei[base + i];
        const int dst = ei[N_EDGES + base + i];
        const int b = dst / BUCK_W;
        const int pos = atomicAdd(&lcur[b], 1);
        pairsP[pos] = ((dst - b * BUCK_W) << 17) | src;
    }
}

// ============ Layer 1: h1 = x@W1a^T + b ; out1 = h1@W1b^T + b ============
__global__ __launch_bounds__(256) void k1_layer1_dense(
    const float* __restrict__ x,
    const float* __restrict__ w1a_w, const float* __restrict__ w1a_b,
    const float* __restrict__ w1b_w, const float* __restrict__ w1b_b,
    ushort_t* __restrict__ h1b, float* __restrict__ out1)
{
    __shared__ float ws[32][256];
    __shared__ float hs[256][36];
    __shared__ float wbs[32][32];

    const int t  = threadIdx.x;
    const int og = t & 3;
    const int ng = t >> 2;
    const int o0 = og * 8;
    const int node0 = blockIdx.x * 256;

    {
        const float4* wsrc = (const float4*)w1a_w;
        float4* wdst = (float4*)&ws[0][0];
        for (int i = t; i < 2048; i += 256) wdst[i] = wsrc[i];
        const float4* bsrc = (const float4*)w1b_w;
        float4* bdst = (float4*)&wbs[0][0];
        if (t < 256) bdst[t] = bsrc[t];
    }
    __syncthreads();

    int nid[4]; bool val[4];
    #pragma unroll
    for (int j = 0; j < 4; ++j) { nid[j] = node0 + ng * 4 + j; val[j] = nid[j] < N_NODES; }

    float acc[4][8] = {};
    for (int kc = 0; kc < 64; kc += 2) {
        float4 xs4[4][2];
        #pragma unroll
        for (int j = 0; j < 4; ++j) {
            if (val[j]) {
                const float4* xr = (const float4*)(x + (size_t)nid[j] * IN_F);
                xs4[j][0] = xr[kc];
                xs4[j][1] = xr[kc + 1];
            } else {
                xs4[j][0] = make_float4(0.f, 0.f, 0.f, 0.f);
                xs4[j][1] = make_float4(0.f, 0.f, 0.f, 0.f);
            }
        }
        #pragma unroll
        for (int u = 0; u < 2; ++u) {
            const int k4 = (kc + u) * 4;
            #pragma unroll
            for (int o = 0; o < 8; ++o) {
                const float4 w4 = *(const float4*)&ws[o0 + o][k4];
                #pragma unroll
                for (int j = 0; j < 4; ++j) {
                    acc[j][o] += xs4[j][u].x * w4.x + xs4[j][u].y * w4.y
                               + xs4[j][u].z * w4.z + xs4[j][u].w * w4.w;
                }
            }
        }
    }

    #pragma unroll
    for (int o = 0; o < 8; ++o) {
        const float b = w1a_b[o0 + o];
        #pragma unroll
        for (int j = 0; j < 4; ++j) acc[j][o] += b;
    }

    #pragma unroll
    for (int j = 0; j < 4; ++j) {
        const int ln = ng * 4 + j;
        *(float4*)&hs[ln][o0]     = make_float4(acc[j][0], acc[j][1], acc[j][2], acc[j][3]);
        *(float4*)&hs[ln][o0 + 4] = make_float4(acc[j][4], acc[j][5], acc[j][6], acc[j][7]);
        if (val[j]) {
            uint4 pk;
            pk.x = (uint_t)f2bf(acc[j][0]) | ((uint_t)f2bf(acc[j][1]) << 16);
            pk.y = (uint_t)f2bf(acc[j][2]) | ((uint_t)f2bf(acc[j][3]) << 16);
            pk.z = (uint_t)f2bf(acc[j][4]) | ((uint_t)f2bf(acc[j][5]) << 16);
            pk.w = (uint_t)f2bf(acc[j][6]) | ((uint_t)f2bf(acc[j][7]) << 16);
            *(uint4*)(h1b + (size_t)nid[j] * HID + o0) = pk;
        }
    }
    __syncthreads();

    float f[4][8] = {};
    #pragma unroll 2
    for (int c4 = 0; c4 < 8; ++c4) {
        float4 h4[4];
        #pragma unroll
        for (int j = 0; j < 4; ++j) h4[j] = *(const float4*)&hs[ng * 4 + j][c4 * 4];
        #pragma unroll
        for (int o = 0; o < 8; ++o) {
            const float4 w4 = *(const float4*)&wbs[o0 + o][c4 * 4];
            #pragma unroll
            for (int j = 0; j < 4; ++j)
                f[j][o] += h4[j].x * w4.x + h4[j].y * w4.y + h4[j].z * w4.z + h4[j].w * w4.w;
        }
    }
    #pragma unroll
    for (int o = 0; o < 8; ++o) {
        const float b = w1b_b[o0 + o];
        #pragma unroll
        for (int j = 0; j < 4; ++j) f[j][o] += b;
    }
    #pragma unroll
    for (int j = 0; j < 4; ++j) {
        if (val[j]) {
            float* dst = out1 + (size_t)nid[j] * HID + o0;
            *(float4*)dst       = make_float4(f[j][0], f[j][1], f[j][2], f[j][3]);
            *(float4*)(dst + 4) = make_float4(f[j][4], f[j][5], f[j][6], f[j][7]);
        }
    }
}

// ============ Aggregate layer 1: block = bucket; LDS f32 accumulate ============
__global__ __launch_bounds__(256) void k_agg32(const int* __restrict__ bstart,
                                               const int* __restrict__ pairsP,
                                               const ushort_t* __restrict__ h1b,
                                               float* __restrict__ out1)
{
    __shared__ float acc[BUCK_W * HID];    // 200*32*4 = 25.6 KB
    const int t = threadIdx.x;
    const int b = blockIdx.x;
    const int c = t & 31;
    const int grp = t >> 5;                // 8 groups
    for (int i = t; i < BUCK_W * HID; i += 256) acc[i] = 0.f;
    __syncthreads();

    const int e0 = bstart[b];
    const int e1 = bstart[b + 1];
    for (int i = e0 + grp; i < e1; i += 8) {
        const int p  = pairsP[i];
        const int rl = p >> 17;
        const int s  = p & 0x1FFFF;
        const float v = bf2f(h1b[(size_t)s * HID + c]);
        atomicAdd(&acc[rl * HID + c], v);   // bank = c -> conflict-free
    }
    __syncthreads();

    float* o = out1 + (size_t)b * BUCK_W * HID;
    for (int i = t; i < BUCK_W * HID; i += 256) o[i] += acc[i];
}

// ============ Layer 2 dense ============
__global__ __launch_bounds__(256) void k3_layer2_dense(
    const float* __restrict__ out1,
    const float* __restrict__ w2a_w, const float* __restrict__ w2a_b,
    const float* __restrict__ w2b_w, const float* __restrict__ w2b_b,
    ushort_t* __restrict__ h2b, float* __restrict__ out2)
{
    __shared__ float rs[64][33];
    __shared__ float h2s[64][17];
    __shared__ float wa[16][33];
    __shared__ float wb[16][17];

    const int t = threadIdx.x;
    const int node0 = blockIdx.x * 64;
    const int nrem = N_NODES - node0;

    for (int i = t; i < 16 * 32; i += 256)
        wa[i >> 5][i & 31] = w2a_w[i];
    if (t < 16 * 16) wb[t >> 4][t & 15] = w2b_w[t];
    for (int i = t; i < 64 * 32; i += 256) {
        int r = i >> 5, c = i & 31;
        float v = 0.f;
        if (r < nrem) v = out1[(size_t)(node0 + r) * HID + c];
        rs[r][c] = fmaxf(v, 0.f);
    }
    __syncthreads();

    const int o = t & 15;
    const int g = t >> 4;

    const float ba = w2a_b[o];
    float acc[4] = {};
    for (int c = 0; c < 32; ++c) {
        const float w = wa[o][c];
        #pragma unroll
        for (int j = 0; j < 4; ++j) acc[j] += rs[g * 4 + j][c] * w;
    }
    #pragma unroll
    for (int j = 0; j < 4; ++j) {
        const int ln = g * 4 + j;
        const float v = acc[j] + ba;
        h2s[ln][o] = v;
        if (ln < nrem) h2b[(size_t)(node0 + ln) * OUTC + o] = f2bf(v);
    }
    __syncthreads();

    const float bbv = w2b_b[o];
    float f[4] = {};
    for (int c = 0; c < 16; ++c) {
        const float w = wb[o][c];
        #pragma unroll
        for (int j = 0; j < 4; ++j) f[j] += h2s[g * 4 + j][c] * w;
    }
    #pragma unroll
    for (int j = 0; j < 4; ++j) {
        const int ln = g * 4 + j;
        if (ln < nrem) out2[(size_t)(node0 + ln) * OUTC + o] = f[j] + bbv;
    }
}

// ============ Aggregate layer 2 + fused log_softmax ============
__global__ __launch_bounds__(256) void k_agg16_sm(const int* __restrict__ bstart,
                                                  const int* __restrict__ pairsP,
                                                  const ushort_t* __restrict__ h2b,
                                                  float* __restrict__ out2)
{
    __shared__ float acc[BUCK_W * OUTC];   // 200*16*4 = 12.8 KB
    const int t = threadIdx.x;
    const int b = blockIdx.x;
    const int c = t & 15;
    const int grp = t >> 4;                // 16 groups
    for (int i = t; i < BUCK_W * OUTC; i += 256) acc[i] = 0.f;
    __syncthreads();

    const int e0 = bstart[b];
    const int e1 = bstart[b + 1];
    for (int i = e0 + grp; i < e1; i += 16) {
        const int p  = pairsP[i];
        const int rl = p >> 17;
        const int s  = p & 0x1FFFF;
        const float v = bf2f(h2b[(size_t)s * OUTC + c]);
        atomicAdd(&acc[rl * OUTC + c], v);
    }
    __syncthreads();

    const int nbase = b * BUCK_W;
    for (int r0 = 0; r0 < BUCK_W; r0 += 16) {
        const int r = r0 + grp;            // uniform within 16-lane group
        if (r < BUCK_W) {
            const int n = nbase + r;
            const float val = out2[(size_t)n * OUTC + c] + acc[r * OUTC + c];
            float m = val;
            #pragma unroll
            for (int off = 8; off > 0; off >>= 1)
                m = fmaxf(m, __shfl_xor(m, off, 16));
            float s = expf(val - m);
            #pragma unroll
            for (int off = 8; off > 0; off >>= 1)
                s += __shfl_xor(s, off, 16);
            const float lse = m + logf(s);
            out2[(size_t)n * OUTC + c] = val - lse;
        }
    }
}

extern "C" void kernel_launch(void* const* d_in, const int* in_sizes, int n_in,
                              void* d_out, int out_size, void* d_ws, size_t ws_size,
                              hipStream_t stream)
{
    const float* x      = (const float*)d_in[0];
    const float* w1a_w  = (const float*)d_in[1];
    const float* w1a_b  = (const float*)d_in[2];
    const float* w1b_w  = (const float*)d_in[3];
    const float* w1b_b  = (const float*)d_in[4];
    const float* w2a_w  = (const float*)d_in[5];
    const float* w2a_b  = (const float*)d_in[6];
    const float* w2b_w  = (const float*)d_in[7];
    const float* w2b_b  = (const float*)d_in[8];
    const int*   ei     = (const int*)d_in[9];
    float* out = (float*)d_out;

    // workspace (~30 MB)
    float*    out1   = (float*)d_ws;                              // 12.8 MB
    ushort_t* h1b    = (ushort_t*)(out1 + (size_t)N_NODES * HID); // 6.4 MB
    ushort_t* h2b    = h1b + (size_t)N_NODES * HID;               // 3.2 MB
    int*      pairsP = (int*)(h2b + (size_t)N_NODES * OUTC);      // 6.4 MB
    int*      bhist  = pairsP + N_EDGES;                          // 500*256 = 512 KB
    int*      boffB  = bhist + NBUCK * NBB;                       // 512 KB
    int*      btot   = boffB + NBUCK * NBB;                       // 500
    int*      bstart = btot + NBUCK;                              // 501

    k_cnt   <<<NBB, 256, 0, stream>>>(ei, bhist);
    k_scanH <<<NBUCK, 256, 0, stream>>>(bhist, boffB, btot);
    k_scanH2<<<1, 512, 0, stream>>>(btot, bstart);
    k_scat  <<<NBB, 256, 0, stream>>>(ei, boffB, bstart, pairsP);

    k1_layer1_dense<<<(N_NODES + 255) / 256, 256, 0, stream>>>(x, w1a_w, w1a_b, w1b_w, w1b_b, h1b, out1);
    k_agg32<<<NBUCK, 256, 0, stream>>>(bstart, pairsP, h1b, out1);
    k3_layer2_dense<<<(N_NODES + 63) / 64, 256, 0, stream>>>(out1, w2a_w, w2a_b, w2b_w, w2b_b, h2b, out);
    k_agg16_sm<<<NBUCK, 256, 0, stream>>>(bstart, pairsP, h2b, out);
}

// Round 8
// 528.364 us; speedup vs baseline: 4.9757x; 1.0368x over previous
//
#include <hip/hip_runtime.h>
#include <hip/hip_bf16.h>
#include <math.h>

#define N_NODES 100000
#define N_EDGES 1600000
#define IN_F 256
#define HID 32
#define OUTC 16
#define NBUCK 500
#define BUCK_W 200     // NBUCK * BUCK_W == N_NODES
#define NBB 256        // partition blocks
#define CHUNK 6250     // N_EDGES / NBB

typedef unsigned short ushort_t;
typedef unsigned int uint_t;

__device__ inline ushort_t f2bf(float f) {
    union { float f; uint_t u; } v; v.f = f;
    uint_t r = v.u + 0x7fff + ((v.u >> 16) & 1);   // round-to-nearest-even
    return (ushort_t)(r >> 16);
}
__device__ inline float bf2f(ushort_t h) {
    union { uint_t u; float f; } v; v.u = (uint_t)h << 16;
    return v.f;
}

// ============ Pass 1: per-block bucket histogram (LDS only, no global atomics) ============
__global__ __launch_bounds__(256) void k_cnt(const int* __restrict__ ei, int* __restrict__ bhist)
{
    __shared__ int lh[NBUCK];
    const int t = threadIdx.x;
    const int blk = blockIdx.x;
    for (int b = t; b < NBUCK; b += 256) lh[b] = 0;
    __syncthreads();
    const int base = blk * CHUNK;
    for (int i = t; i < CHUNK; i += 256) {
        const int dst = ei[N_EDGES + base + i];
        atomicAdd(&lh[dst / BUCK_W], 1);
    }
    __syncthreads();
    for (int b = t; b < NBUCK; b += 256) bhist[b * NBB + blk] = lh[b];
}

// ============ Pass 2a: scan each bucket's 256 block-counts ============
__global__ __launch_bounds__(256) void k_scanH(const int* __restrict__ bhist,
                                               int* __restrict__ boffB, int* __restrict__ btot)
{
    __shared__ int sh[256];
    const int t = threadIdx.x;
    const int b = blockIdx.x;
    const int v = bhist[b * NBB + t];
    sh[t] = v;
    __syncthreads();
    #pragma unroll
    for (int off = 1; off < 256; off <<= 1) {
        const int u = (t >= off) ? sh[t - off] : 0;
        __syncthreads();
        sh[t] += u;
        __syncthreads();
    }
    boffB[b * NBB + t] = sh[t] - v;          // exclusive within bucket
    if (t == 255) btot[b] = sh[255];
}

// ============ Pass 2b: scan bucket totals -> bucket start offsets ============
__global__ __launch_bounds__(512) void k_scanH2(const int* __restrict__ btot,
                                                int* __restrict__ bstart)
{
    __shared__ int sh[512];
    const int t = threadIdx.x;
    const int v = (t < NBUCK) ? btot[t] : 0;
    sh[t] = v;
    __syncthreads();
    #pragma unroll
    for (int off = 1; off < 512; off <<= 1) {
        const int u = (t >= off) ? sh[t - off] : 0;
        __syncthreads();
        sh[t] += u;
        __syncthreads();
    }
    if (t < NBUCK) bstart[t] = sh[t] - v;
    if (t == NBUCK - 1) bstart[NBUCK] = sh[t];
}

// ============ Pass 3: scatter edges into bucket-contiguous packed pairs ============
// pairsP[pos] = (dst % BUCK_W) << 17 | src    (src < 2^17, dstLocal < 2^8)
__global__ __launch_bounds__(256) void k_scat(const int* __restrict__ ei,
                                              const int* __restrict__ boffB,
                                              const int* __restrict__ bstart,
                                              int* __restrict__ pairsP)
{
    __shared__ int lcur[NBUCK];
    const int t = threadIdx.x;
    const int blk = blockIdx.x;
    for (int b = t; b < NBUCK; b += 256) lcur[b] = bstart[b] + boffB[b * NBB + blk];
    __syncthreads();
    const int base = blk * CHUNK;
    for (int i = t; i < CHUNK; i += 256) {
        const int src = ei[base + i];
        const int dst = ei[N_EDGES + base + i];
        const int b = dst / BUCK_W;
        const int pos = atomicAdd(&lcur[b], 1);
        pairsP[pos] = ((dst - b * BUCK_W) << 17) | src;
    }
}

// ============ Layer 1: h1 = x@W1a^T + b ; out1 = h1@W1b^T + b ============
__global__ __launch_bounds__(256) void k1_layer1_dense(
    const float* __restrict__ x,
    const float* __restrict__ w1a_w, const float* __restrict__ w1a_b,
    const float* __restrict__ w1b_w, const float* __restrict__ w1b_b,
    ushort_t* __restrict__ h1b, float* __restrict__ out1)
{
    __shared__ float ws[32][256];
    __shared__ float hs[256][36];
    __shared__ float wbs[32][32];

    const int t  = threadIdx.x;
    const int og = t & 3;
    const int ng = t >> 2;
    const int o0 = og * 8;
    const int node0 = blockIdx.x * 256;

    {
        const float4* wsrc = (const float4*)w1a_w;
        float4* wdst = (float4*)&ws[0][0];
        for (int i = t; i < 2048; i += 256) wdst[i] = wsrc[i];
        const float4* bsrc = (const float4*)w1b_w;
        float4* bdst = (float4*)&wbs[0][0];
        if (t < 256) bdst[t] = bsrc[t];
    }
    __syncthreads();

    int nid[4]; bool val[4];
    #pragma unroll
    for (int j = 0; j < 4; ++j) { nid[j] = node0 + ng * 4 + j; val[j] = nid[j] < N_NODES; }

    float acc[4][8] = {};
    for (int kc = 0; kc < 64; kc += 2) {
        float4 xs4[4][2];
        #pragma unroll
        for (int j = 0; j < 4; ++j) {
            if (val[j]) {
                const float4* xr = (const float4*)(x + (size_t)nid[j] * IN_F);
                xs4[j][0] = xr[kc];
                xs4[j][1] = xr[kc + 1];
            } else {
                xs4[j][0] = make_float4(0.f, 0.f, 0.f, 0.f);
                xs4[j][1] = make_float4(0.f, 0.f, 0.f, 0.f);
            }
        }
        #pragma unroll
        for (int u = 0; u < 2; ++u) {
            const int k4 = (kc + u) * 4;
            #pragma unroll
            for (int o = 0; o < 8; ++o) {
                const float4 w4 = *(const float4*)&ws[o0 + o][k4];
                #pragma unroll
                for (int j = 0; j < 4; ++j) {
                    acc[j][o] += xs4[j][u].x * w4.x + xs4[j][u].y * w4.y
                               + xs4[j][u].z * w4.z + xs4[j][u].w * w4.w;
                }
            }
        }
    }

    #pragma unroll
    for (int o = 0; o < 8; ++o) {
        const float b = w1a_b[o0 + o];
        #pragma unroll
        for (int j = 0; j < 4; ++j) acc[j][o] += b;
    }

    #pragma unroll
    for (int j = 0; j < 4; ++j) {
        const int ln = ng * 4 + j;
        *(float4*)&hs[ln][o0]     = make_float4(acc[j][0], acc[j][1], acc[j][2], acc[j][3]);
        *(float4*)&hs[ln][o0 + 4] = make_float4(acc[j][4], acc[j][5], acc[j][6], acc[j][7]);
        if (val[j]) {
            uint4 pk;
            pk.x = (uint_t)f2bf(acc[j][0]) | ((uint_t)f2bf(acc[j][1]) << 16);
            pk.y = (uint_t)f2bf(acc[j][2]) | ((uint_t)f2bf(acc[j][3]) << 16);
            pk.z = (uint_t)f2bf(acc[j][4]) | ((uint_t)f2bf(acc[j][5]) << 16);
            pk.w = (uint_t)f2bf(acc[j][6]) | ((uint_t)f2bf(acc[j][7]) << 16);
            *(uint4*)(h1b + (size_t)nid[j] * HID + o0) = pk;
        }
    }
    __syncthreads();

    float f[4][8] = {};
    #pragma unroll 2
    for (int c4 = 0; c4 < 8; ++c4) {
        float4 h4[4];
        #pragma unroll
        for (int j = 0; j < 4; ++j) h4[j] = *(const float4*)&hs[ng * 4 + j][c4 * 4];
        #pragma unroll
        for (int o = 0; o < 8; ++o) {
            const float4 w4 = *(const float4*)&wbs[o0 + o][c4 * 4];
            #pragma unroll
            for (int j = 0; j < 4; ++j)
                f[j][o] += h4[j].x * w4.x + h4[j].y * w4.y + h4[j].z * w4.z + h4[j].w * w4.w;
        }
    }
    #pragma unroll
    for (int o = 0; o < 8; ++o) {
        const float b = w1b_b[o0 + o];
        #pragma unroll
        for (int j = 0; j < 4; ++j) f[j][o] += b;
    }
    #pragma unroll
    for (int j = 0; j < 4; ++j) {
        if (val[j]) {
            float* dst = out1 + (size_t)nid[j] * HID + o0;
            *(float4*)dst       = make_float4(f[j][0], f[j][1], f[j][2], f[j][3]);
            *(float4*)(dst + 4) = make_float4(f[j][4], f[j][5], f[j][6], f[j][7]);
        }
    }
}

// ============ Aggregate layer 1: block = bucket; LDS f32 accumulate ============
// 1024 threads = 32 edge-groups of 32 lanes; 4-deep unrolled gathers for ILP.
__global__ __launch_bounds__(1024) void k_agg32(const int* __restrict__ bstart,
                                                const int* __restrict__ pairsP,
                                                const ushort_t* __restrict__ h1b,
                                                float* __restrict__ out1)
{
    __shared__ float acc[BUCK_W * HID];    // 25.6 KB
    const int t = threadIdx.x;
    const int b = blockIdx.x;
    const int c = t & 31;
    const int grp = t >> 5;                // 32 groups
    const int NG = 32;
    for (int i = t; i < BUCK_W * HID; i += 1024) acc[i] = 0.f;
    __syncthreads();

    const int e0 = bstart[b];
    const int e1 = bstart[b + 1];
    int i = e0 + grp;
    for (; i + 3 * NG < e1; i += 4 * NG) {
        const int p0 = pairsP[i];
        const int p1 = pairsP[i + NG];
        const int p2 = pairsP[i + 2 * NG];
        const int p3 = pairsP[i + 3 * NG];
        const float v0 = bf2f(h1b[(size_t)(p0 & 0x1FFFF) * HID + c]);
        const float v1 = bf2f(h1b[(size_t)(p1 & 0x1FFFF) * HID + c]);
        const float v2 = bf2f(h1b[(size_t)(p2 & 0x1FFFF) * HID + c]);
        const float v3 = bf2f(h1b[(size_t)(p3 & 0x1FFFF) * HID + c]);
        atomicAdd(&acc[(p0 >> 17) * HID + c], v0);   // bank = c -> 2 lanes/bank (free)
        atomicAdd(&acc[(p1 >> 17) * HID + c], v1);
        atomicAdd(&acc[(p2 >> 17) * HID + c], v2);
        atomicAdd(&acc[(p3 >> 17) * HID + c], v3);
    }
    for (; i < e1; i += NG) {
        const int p = pairsP[i];
        const float v = bf2f(h1b[(size_t)(p & 0x1FFFF) * HID + c]);
        atomicAdd(&acc[(p >> 17) * HID + c], v);
    }
    __syncthreads();

    float* o = out1 + (size_t)b * BUCK_W * HID;
    for (int k = t; k < BUCK_W * HID; k += 1024) o[k] += acc[k];
}

// ============ Layer 2 dense ============
__global__ __launch_bounds__(256) void k3_layer2_dense(
    const float* __restrict__ out1,
    const float* __restrict__ w2a_w, const float* __restrict__ w2a_b,
    const float* __restrict__ w2b_w, const float* __restrict__ w2b_b,
    ushort_t* __restrict__ h2b, float* __restrict__ out2)
{
    __shared__ float rs[64][33];
    __shared__ float h2s[64][17];
    __shared__ float wa[16][33];
    __shared__ float wb[16][17];

    const int t = threadIdx.x;
    const int node0 = blockIdx.x * 64;
    const int nrem = N_NODES - node0;

    for (int i = t; i < 16 * 32; i += 256)
        wa[i >> 5][i & 31] = w2a_w[i];
    if (t < 16 * 16) wb[t >> 4][t & 15] = w2b_w[t];
    for (int i = t; i < 64 * 32; i += 256) {
        int r = i >> 5, c = i & 31;
        float v = 0.f;
        if (r < nrem) v = out1[(size_t)(node0 + r) * HID + c];
        rs[r][c] = fmaxf(v, 0.f);
    }
    __syncthreads();

    const int o = t & 15;
    const int g = t >> 4;

    const float ba = w2a_b[o];
    float acc[4] = {};
    for (int c = 0; c < 32; ++c) {
        const float w = wa[o][c];
        #pragma unroll
        for (int j = 0; j < 4; ++j) acc[j] += rs[g * 4 + j][c] * w;
    }
    #pragma unroll
    for (int j = 0; j < 4; ++j) {
        const int ln = g * 4 + j;
        const float v = acc[j] + ba;
        h2s[ln][o] = v;
        if (ln < nrem) h2b[(size_t)(node0 + ln) * OUTC + o] = f2bf(v);
    }
    __syncthreads();

    const float bbv = w2b_b[o];
    float f[4] = {};
    for (int c = 0; c < 16; ++c) {
        const float w = wb[o][c];
        #pragma unroll
        for (int j = 0; j < 4; ++j) f[j] += h2s[g * 4 + j][c] * w;
    }
    #pragma unroll
    for (int j = 0; j < 4; ++j) {
        const int ln = g * 4 + j;
        if (ln < nrem) out2[(size_t)(node0 + ln) * OUTC + o] = f[j] + bbv;
    }
}

// ============ Aggregate layer 2 + fused log_softmax ============
// 1024 threads = 64 edge-groups of 16 lanes; 4-deep unrolled gathers.
__global__ __launch_bounds__(1024) void k_agg16_sm(const int* __restrict__ bstart,
                                                   const int* __restrict__ pairsP,
                                                   const ushort_t* __restrict__ h2b,
                                                   float* __restrict__ out2)
{
    __shared__ float acc[BUCK_W * OUTC];   // 12.8 KB
    const int t = threadIdx.x;
    const int b = blockIdx.x;
    const int c = t & 15;
    const int grp = t >> 4;                // 64 groups
    const int NG = 64;
    for (int i = t; i < BUCK_W * OUTC; i += 1024) acc[i] = 0.f;
    __syncthreads();

    const int e0 = bstart[b];
    const int e1 = bstart[b + 1];
    int i = e0 + grp;
    for (; i + 3 * NG < e1; i += 4 * NG) {
        const int p0 = pairsP[i];
        const int p1 = pairsP[i + NG];
        const int p2 = pairsP[i + 2 * NG];
        const int p3 = pairsP[i + 3 * NG];
        const float v0 = bf2f(h2b[(size_t)(p0 & 0x1FFFF) * OUTC + c]);
        const float v1 = bf2f(h2b[(size_t)(p1 & 0x1FFFF) * OUTC + c]);
        const float v2 = bf2f(h2b[(size_t)(p2 & 0x1FFFF) * OUTC + c]);
        const float v3 = bf2f(h2b[(size_t)(p3 & 0x1FFFF) * OUTC + c]);
        atomicAdd(&acc[(p0 >> 17) * OUTC + c], v0);
        atomicAdd(&acc[(p1 >> 17) * OUTC + c], v1);
        atomicAdd(&acc[(p2 >> 17) * OUTC + c], v2);
        atomicAdd(&acc[(p3 >> 17) * OUTC + c], v3);
    }
    for (; i < e1; i += NG) {
        const int p = pairsP[i];
        const float v = bf2f(h2b[(size_t)(p & 0x1FFFF) * OUTC + c]);
        atomicAdd(&acc[(p >> 17) * OUTC + c], v);
    }
    __syncthreads();

    const int nbase = b * BUCK_W;
    for (int r = grp; r < BUCK_W; r += 64) {
        const int n = nbase + r;
        const float val = out2[(size_t)n * OUTC + c] + acc[r * OUTC + c];
        float m = val;
        #pragma unroll
        for (int off = 8; off > 0; off >>= 1)
            m = fmaxf(m, __shfl_xor(m, off, 16));
        float s = expf(val - m);
        #pragma unroll
        for (int off = 8; off > 0; off >>= 1)
            s += __shfl_xor(s, off, 16);
        const float lse = m + logf(s);
        out2[(size_t)n * OUTC + c] = val - lse;
    }
}

extern "C" void kernel_launch(void* const* d_in, const int* in_sizes, int n_in,
                              void* d_out, int out_size, void* d_ws, size_t ws_size,
                              hipStream_t stream)
{
    const float* x      = (const float*)d_in[0];
    const float* w1a_w  = (const float*)d_in[1];
    const float* w1a_b  = (const float*)d_in[2];
    const float* w1b_w  = (const float*)d_in[3];
    const float* w1b_b  = (const float*)d_in[4];
    const float* w2a_w  = (const float*)d_in[5];
    const float* w2a_b  = (const float*)d_in[6];
    const float* w2b_w  = (const float*)d_in[7];
    const float* w2b_b  = (const float*)d_in[8];
    const int*   ei     = (const int*)d_in[9];
    float* out = (float*)d_out;

    // workspace (~30 MB)
    float*    out1   = (float*)d_ws;                              // 12.8 MB
    ushort_t* h1b    = (ushort_t*)(out1 + (size_t)N_NODES * HID); // 6.4 MB
    ushort_t* h2b    = h1b + (size_t)N_NODES * HID;               // 3.2 MB
    int*      pairsP = (int*)(h2b + (size_t)N_NODES * OUTC);      // 6.4 MB
    int*      bhist  = pairsP + N_EDGES;                          // 500*256 = 512 KB
    int*      boffB  = bhist + NBUCK * NBB;                       // 512 KB
    int*      btot   = boffB + NBUCK * NBB;                       // 500
    int*      bstart = btot + NBUCK;                              // 501

    k_cnt   <<<NBB, 256, 0, stream>>>(ei, bhist);
    k_scanH <<<NBUCK, 256, 0, stream>>>(bhist, boffB, btot);
    k_scanH2<<<1, 512, 0, stream>>>(btot, bstart);
    k_scat  <<<NBB, 256, 0, stream>>>(ei, boffB, bstart, pairsP);

    k1_layer1_dense<<<(N_NODES + 255) / 256, 256, 0, stream>>>(x, w1a_w, w1a_b, w1b_w, w1b_b, h1b, out1);
    k_agg32<<<NBUCK, 1024, 0, stream>>>(bstart, pairsP, h1b, out1);
    k3_layer2_dense<<<(N_NODES + 63) / 64, 256, 0, stream>>>(out1, w2a_w, w2a_b, w2b_w, w2b_b, h2b, out);
    k_agg16_sm<<<NBUCK, 1024, 0, stream>>>(bstart, pairsP, h2b, out);
}